// Round 20
// baseline (89.911 us; speedup 1.0000x reference)
//
#include <hip/hip_runtime.h>
#include <hip/hip_cooperative_groups.h>

namespace cg = cooperative_groups;

// T=2^21 sequential nonlinear storage recurrence + per-column z-score.
// R20 = R19 fused into ONE cooperative kernel: scan -> per-block partials ->
// grid.sync() -> each block reduces the 512 partials itself -> normalizes its
// own 4096 rows (x re-read L2-warm; pn/en recomputed; ps/perc from a 32KB
// swizzled LDS array written at emit). Eliminates the 33.6MB side round-trip,
// 2 dispatch gaps, and the finalize dispatch. LDS 75.9KB -> still 2 blocks/CU.
// Fallback: R19's 3-kernel path if cooperative launch unsupported.

#define T_TOTAL   (1 << 21)
#define C_CHUNKS  (T_TOTAL / 16)             // 131072
#define NTAIL     128
#define THREADS   256
#define NBLOCKS   (C_CHUNKS / THREADS)       // 512 -> exactly 2 blocks/CU
#define NSTAGE4   2376                       // float4s staged per block
#define LDSN      4768                       // float2 slots (need 4752)
#define NWIN      287                        // windows per block
#define X4MAX     (T_TOTAL / 2 - 1)
#define C49       0.44444445f

// ws layout (bytes)
#define OFF_SP    0                                   // [12][512] double
#define OFF_MUSIG 49152                               // 12 float (fallback)
#define OFF_SIDE  49664                               // T float2 (fallback)

#define SWZ(w) ((w) ^ (((w) >> 4) & 31))
#define RD(Sb, mm) (*(const float2*)(lbase + ((Sb) ^ ((mm) << 3))))
#define CL(v) fminf(fmaxf((v), 0.0f), rmax)

// window drift: cubic + 16x perc (3-term)
#define DRIFT(RV, C, OUT)                                                  \
    {                                                                      \
        float rr_ = (RV);                                                  \
        float d_ = fmaf(rr_, fmaf(rr_, fmaf(rr_, (C).w, (C).z), (C).y), (C).x); \
        float y_  = rr_ * C49;                                             \
        float y2_ = y_ * y_;                                               \
        float u_  = y2_ * y2_;                                             \
        float pl_ = fmaf(u_, fmaf(u_, 1.875f, -2.5f), 4.0f);               \
        OUT = d_ - (rr_ * u_) * pl_;                                       \
    }

#define CSTEP(C)                                                           \
    {                                                                      \
        float k1_, k2_;                                                    \
        DRIFT(r, C, k1_)                                                   \
        float sm_ = CL(r + k1_);                                           \
        DRIFT(sm_, C, k2_)                                                 \
        r = CL(fmaf(0.5f, k1_ + k2_, r));                                  \
    }

#define WLD(j) make_float4(cA[kp + (j)], cB[kp + (j)], cC[kp + (j)], cD[kp + (j)])

#define CGRP_R(OFF)                                                        \
    CSTEP(c0) c0 = WLD((OFF) + 8);  CSTEP(c1) c1 = WLD((OFF) + 9);         \
    CSTEP(c2) c2 = WLD((OFF) + 10); CSTEP(c3) c3 = WLD((OFF) + 11);        \
    CSTEP(c4) c4 = WLD((OFF) + 12); CSTEP(c5) c5 = WLD((OFF) + 13);        \
    CSTEP(c6) c6 = WLD((OFF) + 14); CSTEP(c7) c7 = WLD((OFF) + 15);
#define CGRP_L                                                             \
    CSTEP(c0) CSTEP(c1) CSTEP(c2) CSTEP(c3)                                \
    CSTEP(c4) CSTEP(c5) CSTEP(c6) CSTEP(c7)

// diet tail step (quadratic drift): inputs a, b2=2b
#define FSTEP(a, b2)                                                       \
    {                                                                      \
        float m_  = fmaf(-0.5f, (b2), (a));            /* a-b */           \
        float rn_ = r + fmaf(r, fmaf(r, -m_, -(b2)), (a));                 \
        float y_  = rn_ * C49; float y2_ = y_ * y_; float u_ = y2_ * y2_;  \
        float pl_ = fmaf(u_, -0.15625f, 0.25f);                            \
        r = rn_ - (rn_ * u_) * pl_;                                        \
    }

// emit step: tanh 2-term, divisor corrections first-order, full perc poly
#define ESTEP(a, b2, PS, PC)                                               \
    {                                                                      \
        float b_   = 0.5f * (b2);                                          \
        float tp_  = (a) * fmaf((a) * (a), -0.33333334f, 1.0f);            \
        float te_  = b_ * fmaf(b_ * b_, -0.33333334f, 1.0f);               \
        float q1_  = fmaf(-r, tp_, 1.0f);              /* 1-e1 */          \
        float dp_  = (tp_ * fmaf(-r, r, 1.0f)) * q1_;                      \
        float omr_ = 1.0f - r;                                             \
        float q2_  = fmaf(-te_, omr_, 1.0f);           /* 1-e2 */          \
        float de_  = ((r * (2.0f - r)) * te_) * q2_;                       \
        float rn_  = r + (dp_ - de_);                                      \
        float y_   = rn_ * C49; float y2_ = y_ * y_; float u_ = y2_ * y2_; \
        float pl_  = fmaf(u_, fmaf(u_, 0.1171875f, -0.15625f), 0.25f);     \
        float pcr_ = (rn_ * u_) * pl_;                                     \
        r = rn_ - pcr_;                                                    \
        PS = x1s * dp_;                                                    \
        PC = x1s * pcr_;                                                   \
    }

// consume ring slot + prefetch 4 ahead
#define FQ(RN, mm)                                                         \
    FSTEP(RN.x, RN.y)                                                      \
    RN = ((mm) < 12) ? RD(Sc, (mm) + 4) : RD(Sn, (mm) - 12);

// ================= fused cooperative kernel =================
// emit pair -> LDS psperc (swizzled)
#define EPAIR2F(RA, RB, m0)                                                \
    {                                                                      \
        float psA, pcA, psB, pcB;                                          \
        ESTEP(RA.x, RA.y, psA, pcA)                                        \
        ESTEP(RB.x, RB.y, psB, pcB)                                        \
        psperc[SWZ(eb + (m0))]     = make_float2(psA, pcA);                \
        psperc[SWZ(eb + (m0) + 1)] = make_float2(psB, pcB);                \
        sum4 += psA + psB; sq4 = fmaf(psA, psA, sq4); sq4 = fmaf(psB, psB, sq4); \
        sum5 += pcA + pcB; sq5 = fmaf(pcA, pcA, sq5); sq5 = fmaf(pcB, pcB, sq5); \
        if ((m0) < 12) { RA = RD(Se, (m0) + 4); RB = RD(Se, (m0) + 5); }   \
    }

__global__ __launch_bounds__(256, 2) void fused_kernel(const float4* __restrict__ x4,
                                                       const float* __restrict__ x1p,
                                                       float* __restrict__ out,
                                                       double* __restrict__ sp) {
    __shared__ float2 plane[LDSN];
    __shared__ float2 psperc[4096];
    __shared__ float cA[NWIN + 1], cB[NWIN + 1], cC[NWIN + 1], cD[NWIN + 1];
    __shared__ double red[4][12];
    __shared__ float sh[12];

    const float x1s    = x1p[0];
    const float inv_x1 = 1.0f / x1s;
    const float inv2x  = 2.0f * inv_x1;
    const float rmax   = 320.0f * inv_x1;
    const int kp = threadIdx.x;
    const char* lbase = (const char*)plane;

    // ---- stage (a,2b) for elements [16k0-640, 16k0+4096+16) + cols0-3 stats
    float s0 = 0, s1 = 0, s2c = 0, s3 = 0, q0 = 0, q1 = 0, q2 = 0, q3 = 0;
    {
        const int g0 = 2048 * blockIdx.x - 320;        // float4 base
        for (int j = 0; j < 10; ++j) {
            int ts = threadIdx.x + 256 * j;
            if (ts < NSTAGE4) {
                int g4 = g0 + ts;
                float4 v = x4[min(max(g4, 0), X4MAX)];
                float pn0 = fmaxf(v.x - v.y, 0.0f), en0 = fmaxf(v.y - v.x, 0.0f);
                float pn1 = fmaxf(v.z - v.w, 0.0f), en1 = fmaxf(v.w - v.z, 0.0f);
                if (g4 < 0) { pn0 = en0 = pn1 = en1 = 0.0f; }
                plane[SWZ(2 * ts)]     = make_float2(pn0 * inv_x1, en0 * inv2x);
                plane[SWZ(2 * ts + 1)] = make_float2(pn1 * inv_x1, en1 * inv2x);
                if (ts >= 320 && ts < 2368) {          // owned emit region
                    s0 += v.x + v.z; q0 = fmaf(v.x, v.x, q0); q0 = fmaf(v.z, v.z, q0);
                    s1 += v.y + v.w; q1 = fmaf(v.y, v.y, q1); q1 = fmaf(v.w, v.w, q1);
                    s2c += pn0 + pn1; q2 = fmaf(pn0, pn0, q2); q2 = fmaf(pn1, pn1, q2);
                    s3 += en0 + en1; q3 = fmaf(en0, en0, q3); q3 = fmaf(en1, en1, q3);
                }
            }
        }
    }
    __syncthreads();

    // ---- per-window drift-cubic coeffs from staged plane (linear tanh) ----
    for (int wl = threadIdx.x; wl < NWIN; wl += 256) {
        const int Sw = SWZ(16 * wl) << 3;
        float Sa = 0, Sa2 = 0, Sb = 0, Sb2 = 0;
#pragma unroll
        for (int mm = 0; mm < 16; ++mm) {
            float2 p = RD(Sw, mm);
            Sa += p.x; Sa2 = fmaf(p.x, p.x, Sa2);
            Sb += p.y; Sb2 = fmaf(p.y, p.y, Sb2);
        }
        float Tp = Sa, Qp = Sa2, Te = 0.5f * Sb, Qe = 0.25f * Sb2;
        cA[wl] = Tp;
        cB[wl] = 2.0f * (Qe - Te) - Qp;
        cC[wl] = Te - Tp - 3.0f * Qe;
        cD[wl] = Qp + Qe;
    }
    __syncthreads();

    // ---- coarse phase: 32 windows ----
    float4 c0 = WLD(0), c1 = WLD(1), c2 = WLD(2), c3 = WLD(3),
           c4 = WLD(4), c5 = WLD(5), c6 = WLD(6), c7 = WLD(7);
    float r = 0.0f;
    CGRP_R(0) CGRP_R(8) CGRP_R(16) CGRP_L

    // ---- exact tail: 128 steps ----
    float2 r0, r1, r2, r3;
    {
        const int S0 = SWZ(16 * kp + 512) << 3;
        r0 = RD(S0, 0); r1 = RD(S0, 1); r2 = RD(S0, 2); r3 = RD(S0, 3);
    }
#pragma unroll 1
    for (int B = 0; B < NTAIL; B += 16) {
        const int W0 = 16 * kp + 512 + B;
        const int Sc = SWZ(W0) << 3;
        const int Sn = SWZ(W0 + 16) << 3;
        FQ(r0, 0)  FQ(r1, 1)  FQ(r2, 2)  FQ(r3, 3)
        FQ(r0, 4)  FQ(r1, 5)  FQ(r2, 6)  FQ(r3, 7)
        FQ(r0, 8)  FQ(r1, 9)  FQ(r2, 10) FQ(r3, 11)
        FQ(r0, 12) FQ(r1, 13) FQ(r2, 14) FQ(r3, 15)
    }

    // ---- exact emit: 16 steps -> LDS psperc ----
    float sum4 = 0, sum5 = 0, sq4 = 0, sq5 = 0;
    const int eb = 16 * kp;
    const int Se = SWZ(16 * kp + 512 + NTAIL) << 3;
    EPAIR2F(r0, r1, 0)  EPAIR2F(r2, r3, 2)
    EPAIR2F(r0, r1, 4)  EPAIR2F(r2, r3, 6)
    EPAIR2F(r0, r1, 8)  EPAIR2F(r2, r3, 10)
    EPAIR2F(r0, r1, 12) EPAIR2F(r2, r3, 14)

    // ---- block reduction -> per-block partials ----
    double vv[12] = {s0, s1, s2c, s3, sum4, sum5,
                     q0, q1, q2, q3, sq4, sq5};
    const int wid = threadIdx.x >> 6, lane = threadIdx.x & 63;
#pragma unroll
    for (int c = 0; c < 12; ++c) {
        double val = vv[c];
        for (int off = 32; off > 0; off >>= 1) val += __shfl_down(val, off, 64);
        if (lane == 0) red[wid][c] = val;
    }
    __syncthreads();
    if (threadIdx.x < 12) {
        int c = threadIdx.x;
        sp[c * 512 + blockIdx.x] = red[0][c] + red[1][c] + red[2][c] + red[3][c];
    }

    // ---- grid-wide sync: all partials visible ----
    cg::this_grid().sync();

    // ---- every block reduces the 512 partials itself -> sh[12] ----
    {
        const int t = threadIdx.x;
#pragma unroll
        for (int c = 0; c < 12; ++c) {
            double v = sp[c * 512 + t] + sp[c * 512 + 256 + t];
            for (int off = 32; off > 0; off >>= 1) v += __shfl_down(v, off, 64);
            if (lane == 0) red[wid][c] = v;
        }
        __syncthreads();
        if (t < 6) {
            double sum = red[0][t] + red[1][t] + red[2][t] + red[3][t];
            double sq  = red[0][6 + t] + red[1][6 + t] + red[2][6 + t] + red[3][6 + t];
            double n = (double)T_TOTAL;
            double mu = sum / n;
            double var = (sq - sum * sum / n) / (n - 1.0);
            sh[t] = (float)mu;
            sh[6 + t] = (float)(1.0 / sqrt(var));
        }
        __syncthreads();
    }

    // ---- normalize own 4096 rows (x re-read, ps/perc from LDS) ----
    {
        float mu[6], is[6];
#pragma unroll
        for (int c = 0; c < 6; ++c) { mu[c] = sh[c]; is[c] = sh[6 + c]; }
        float4* out4 = (float4*)out;
        const int pb = 2048 * blockIdx.x;
        const size_t ob = 6144ull * blockIdx.x;
#pragma unroll 1
        for (int i = 0; i < 8; ++i) {
            int pl = i * 256 + threadIdx.x;            // local row-pair
            float4 xv = x4[pb + pl];
            int lr = 2 * pl;
            float2 P0 = psperc[SWZ(lr)];
            float2 P1 = psperc[SWZ(lr + 1)];
            float pn0 = fmaxf(xv.x - xv.y, 0.0f), en0 = fmaxf(xv.y - xv.x, 0.0f);
            float pn1 = fmaxf(xv.z - xv.w, 0.0f), en1 = fmaxf(xv.w - xv.z, 0.0f);
            float4* o = out4 + ob + 3 * (size_t)pl;
            o[0] = make_float4((xv.x - mu[0]) * is[0], (xv.y - mu[1]) * is[1],
                               (pn0 - mu[2]) * is[2], (en0 - mu[3]) * is[3]);
            o[1] = make_float4((P0.x - mu[4]) * is[4], (P0.y - mu[5]) * is[5],
                               (xv.z - mu[0]) * is[0], (xv.w - mu[1]) * is[1]);
            o[2] = make_float4((pn1 - mu[2]) * is[2], (en1 - mu[3]) * is[3],
                               (P1.x - mu[4]) * is[4], (P1.y - mu[5]) * is[5]);
        }
    }
}

// ================= fallback path (R19, proven 49.0us) =================
#define EPAIR2(RA, RB, m0)                                                 \
    {                                                                      \
        float psA, pcA, psB, pcB;                                          \
        ESTEP(RA.x, RA.y, psA, pcA)                                        \
        ESTEP(RB.x, RB.y, psB, pcB)                                        \
        *(float4*)(side + 2 * (size_t)(t0 + (m0))) =                       \
            make_float4(psA, pcA, psB, pcB);                               \
        sum4 += psA + psB; sq4 = fmaf(psA, psA, sq4); sq4 = fmaf(psB, psB, sq4); \
        sum5 += pcA + pcB; sq5 = fmaf(pcA, pcA, sq5); sq5 = fmaf(pcB, pcB, sq5); \
        if ((m0) < 12) { RA = RD(Se, (m0) + 4); RB = RD(Se, (m0) + 5); }   \
    }

__global__ __launch_bounds__(256, 2) void scan_kernel(const float4* __restrict__ x4,
                                                      const float* __restrict__ x1p,
                                                      float* __restrict__ side,
                                                      double* __restrict__ sp) {
    __shared__ float2 plane[LDSN];
    __shared__ float cA[NWIN + 1], cB[NWIN + 1], cC[NWIN + 1], cD[NWIN + 1];
    __shared__ double red[4][12];

    const float x1s    = x1p[0];
    const float inv_x1 = 1.0f / x1s;
    const float inv2x  = 2.0f * inv_x1;
    const float rmax   = 320.0f * inv_x1;
    const int k  = blockIdx.x * 256 + threadIdx.x;
    const int kp = threadIdx.x;
    const char* lbase = (const char*)plane;

    float s0 = 0, s1 = 0, s2c = 0, s3 = 0, q0 = 0, q1 = 0, q2 = 0, q3 = 0;
    {
        const int g0 = 2048 * blockIdx.x - 320;
        for (int j = 0; j < 10; ++j) {
            int ts = threadIdx.x + 256 * j;
            if (ts < NSTAGE4) {
                int g4 = g0 + ts;
                float4 v = x4[min(max(g4, 0), X4MAX)];
                float pn0 = fmaxf(v.x - v.y, 0.0f), en0 = fmaxf(v.y - v.x, 0.0f);
                float pn1 = fmaxf(v.z - v.w, 0.0f), en1 = fmaxf(v.w - v.z, 0.0f);
                if (g4 < 0) { pn0 = en0 = pn1 = en1 = 0.0f; }
                plane[SWZ(2 * ts)]     = make_float2(pn0 * inv_x1, en0 * inv2x);
                plane[SWZ(2 * ts + 1)] = make_float2(pn1 * inv_x1, en1 * inv2x);
                if (ts >= 320 && ts < 2368) {
                    s0 += v.x + v.z; q0 = fmaf(v.x, v.x, q0); q0 = fmaf(v.z, v.z, q0);
                    s1 += v.y + v.w; q1 = fmaf(v.y, v.y, q1); q1 = fmaf(v.w, v.w, q1);
                    s2c += pn0 + pn1; q2 = fmaf(pn0, pn0, q2); q2 = fmaf(pn1, pn1, q2);
                    s3 += en0 + en1; q3 = fmaf(en0, en0, q3); q3 = fmaf(en1, en1, q3);
                }
            }
        }
    }
    __syncthreads();

    for (int wl = threadIdx.x; wl < NWIN; wl += 256) {
        const int Sw = SWZ(16 * wl) << 3;
        float Sa = 0, Sa2 = 0, Sb = 0, Sb2 = 0;
#pragma unroll
        for (int mm = 0; mm < 16; ++mm) {
            float2 p = RD(Sw, mm);
            Sa += p.x; Sa2 = fmaf(p.x, p.x, Sa2);
            Sb += p.y; Sb2 = fmaf(p.y, p.y, Sb2);
        }
        float Tp = Sa, Qp = Sa2, Te = 0.5f * Sb, Qe = 0.25f * Sb2;
        cA[wl] = Tp;
        cB[wl] = 2.0f * (Qe - Te) - Qp;
        cC[wl] = Te - Tp - 3.0f * Qe;
        cD[wl] = Qp + Qe;
    }
    __syncthreads();

    float4 c0 = WLD(0), c1 = WLD(1), c2 = WLD(2), c3 = WLD(3),
           c4 = WLD(4), c5 = WLD(5), c6 = WLD(6), c7 = WLD(7);
    float r = 0.0f;
    CGRP_R(0) CGRP_R(8) CGRP_R(16) CGRP_L

    float2 r0, r1, r2, r3;
    {
        const int S0 = SWZ(16 * kp + 512) << 3;
        r0 = RD(S0, 0); r1 = RD(S0, 1); r2 = RD(S0, 2); r3 = RD(S0, 3);
    }
#pragma unroll 1
    for (int B = 0; B < NTAIL; B += 16) {
        const int W0 = 16 * kp + 512 + B;
        const int Sc = SWZ(W0) << 3;
        const int Sn = SWZ(W0 + 16) << 3;
        FQ(r0, 0)  FQ(r1, 1)  FQ(r2, 2)  FQ(r3, 3)
        FQ(r0, 4)  FQ(r1, 5)  FQ(r2, 6)  FQ(r3, 7)
        FQ(r0, 8)  FQ(r1, 9)  FQ(r2, 10) FQ(r3, 11)
        FQ(r0, 12) FQ(r1, 13) FQ(r2, 14) FQ(r3, 15)
    }

    float sum4 = 0, sum5 = 0, sq4 = 0, sq5 = 0;
    const int t0 = 16 * k;
    const int Se = SWZ(16 * kp + 512 + NTAIL) << 3;
    EPAIR2(r0, r1, 0)  EPAIR2(r2, r3, 2)
    EPAIR2(r0, r1, 4)  EPAIR2(r2, r3, 6)
    EPAIR2(r0, r1, 8)  EPAIR2(r2, r3, 10)
    EPAIR2(r0, r1, 12) EPAIR2(r2, r3, 14)

    double vv[12] = {s0, s1, s2c, s3, sum4, sum5,
                     q0, q1, q2, q3, sq4, sq5};
    const int wid = threadIdx.x >> 6, lane = threadIdx.x & 63;
#pragma unroll
    for (int c = 0; c < 12; ++c) {
        double val = vv[c];
        for (int off = 32; off > 0; off >>= 1) val += __shfl_down(val, off, 64);
        if (lane == 0) red[wid][c] = val;
    }
    __syncthreads();
    if (threadIdx.x < 12) {
        int c = threadIdx.x;
        sp[c * 512 + blockIdx.x] = red[0][c] + red[1][c] + red[2][c] + red[3][c];
    }
}

__global__ __launch_bounds__(256) void finalize_kernel(const double* __restrict__ sp,
                                                       float* __restrict__ musig) {
    __shared__ double red[12][4];
    const int t = threadIdx.x, lane = t & 63, wid = t >> 6;
#pragma unroll
    for (int c = 0; c < 12; ++c) {
        double v = sp[c * 512 + t] + sp[c * 512 + 256 + t];
        for (int off = 32; off > 0; off >>= 1) v += __shfl_down(v, off, 64);
        if (lane == 0) red[c][wid] = v;
    }
    __syncthreads();
    if (t < 6) {
        double sum = red[t][0] + red[t][1] + red[t][2] + red[t][3];
        double sq  = red[6 + t][0] + red[6 + t][1] + red[6 + t][2] + red[6 + t][3];
        double n = (double)T_TOTAL;
        double mu = sum / n;
        double var = (sq - sum * sum / n) / (n - 1.0);
        musig[t] = (float)mu;
        musig[6 + t] = (float)(1.0 / sqrt(var));
    }
}

__global__ __launch_bounds__(256) void normalize_kernel(const float4* __restrict__ xp4,
                                                        const float4* __restrict__ side4,
                                                        float* __restrict__ out,
                                                        const float* __restrict__ musig) {
    float mu[6], is[6];
#pragma unroll
    for (int c = 0; c < 6; ++c) { mu[c] = musig[c]; is[c] = musig[6 + c]; }

    int idx = blockIdx.x * blockDim.x + threadIdx.x;
    int stride = gridDim.x * blockDim.x;
    for (int p = idx; p < T_TOTAL / 2; p += stride) {
        float4 xv = xp4[p];
        float* o = out + 12 * (size_t)p;
        float4 sv = side4[p];
        float pn0 = fmaxf(xv.x - xv.y, 0.0f), en0 = fmaxf(xv.y - xv.x, 0.0f);
        float pn1 = fmaxf(xv.z - xv.w, 0.0f), en1 = fmaxf(xv.w - xv.z, 0.0f);
        float4 o0 = {(xv.x - mu[0]) * is[0], (xv.y - mu[1]) * is[1],
                     (pn0 - mu[2]) * is[2], (en0 - mu[3]) * is[3]};
        float4 o1 = {(sv.x - mu[4]) * is[4], (sv.y - mu[5]) * is[5],
                     (xv.z - mu[0]) * is[0], (xv.w - mu[1]) * is[1]};
        float4 o2 = {(pn1 - mu[2]) * is[2], (en1 - mu[3]) * is[3],
                     (sv.z - mu[4]) * is[4], (sv.w - mu[5]) * is[5]};
        *(float4*)(o + 0) = o0;
        *(float4*)(o + 4) = o1;
        *(float4*)(o + 8) = o2;
    }
}

extern "C" void kernel_launch(void* const* d_in, const int* in_sizes, int n_in,
                              void* d_out, int out_size, void* d_ws, size_t ws_size,
                              hipStream_t stream) {
    const float4* x4 = (const float4*)d_in[0];
    const float* x1 = (const float*)d_in[1];
    float* out = (float*)d_out;
    char* ws = (char*)d_ws;
    double* sp = (double*)(ws + OFF_SP);
    float* musig = (float*)(ws + OFF_MUSIG);
    float* side = (float*)(ws + OFF_SIDE);

    int coop = 0;
    hipDeviceGetAttribute(&coop, hipDeviceAttributeCooperativeLaunch, 0);
    const bool big_ws = ws_size >= (size_t)OFF_SIDE + (size_t)T_TOTAL * 8;

    if (coop) {
        void* args[] = {(void*)&x4, (void*)&x1, (void*)&out, (void*)&sp};
        hipLaunchCooperativeKernel((void*)fused_kernel, dim3(NBLOCKS),
                                   dim3(THREADS), args, 0, stream);
    } else if (big_ws) {
        scan_kernel<<<NBLOCKS, THREADS, 0, stream>>>(x4, x1, side, sp);
        finalize_kernel<<<1, 256, 0, stream>>>(sp, musig);
        normalize_kernel<<<2048, 256, 0, stream>>>(x4, (const float4*)side, out, musig);
    }
}

// Round 21
// 50.140 us; speedup vs baseline: 1.7932x; 1.7932x over previous
//
#include <hip/hip_runtime.h>

// T=2^21 sequential nonlinear storage recurrence + per-column z-score.
// R21 = R19 (best: 49.0us) minus the finalize dispatch: scan block-reduces
// 12 stat channels and atomicAdds into 12 global doubles (6K atomics total);
// normalize computes mu/sigma in its prologue. 2 dispatches + 96B memset.
// (R20's cooperative grid.sync cost ~35us on this shape -- refuted.)

#define T_TOTAL   (1 << 21)
#define C_CHUNKS  (T_TOTAL / 16)             // 131072
#define NTAIL     128
#define THREADS   256
#define NBLOCKS   (C_CHUNKS / THREADS)       // 512 -> 2 blocks/CU
#define NSTAGE4   2376                       // float4s staged per block
#define LDSN      4768                       // float2 slots (need 4752)
#define NWIN      287                        // windows per block
#define X4MAX     (T_TOTAL / 2 - 1)
#define C49       0.44444445f

// ws layout (bytes)
#define OFF_STATS 0                                   // 12 double
#define OFF_SIDE  1024                                // T float2 (ps,perc)

#define SWZ(w) ((w) ^ (((w) >> 4) & 31))
#define RD(Sb, mm) (*(const float2*)(lbase + ((Sb) ^ ((mm) << 3))))
#define CL(v) fminf(fmaxf((v), 0.0f), rmax)

// window drift: cubic + 16x perc (3-term)
#define DRIFT(RV, C, OUT)                                                  \
    {                                                                      \
        float rr_ = (RV);                                                  \
        float d_ = fmaf(rr_, fmaf(rr_, fmaf(rr_, (C).w, (C).z), (C).y), (C).x); \
        float y_  = rr_ * C49;                                             \
        float y2_ = y_ * y_;                                               \
        float u_  = y2_ * y2_;                                             \
        float pl_ = fmaf(u_, fmaf(u_, 1.875f, -2.5f), 4.0f);               \
        OUT = d_ - (rr_ * u_) * pl_;                                       \
    }

#define CSTEP(C)                                                           \
    {                                                                      \
        float k1_, k2_;                                                    \
        DRIFT(r, C, k1_)                                                   \
        float sm_ = CL(r + k1_);                                           \
        DRIFT(sm_, C, k2_)                                                 \
        r = CL(fmaf(0.5f, k1_ + k2_, r));                                  \
    }

#define WLD(j) make_float4(cA[kp + (j)], cB[kp + (j)], cC[kp + (j)], cD[kp + (j)])

#define CGRP_R(OFF)                                                        \
    CSTEP(c0) c0 = WLD((OFF) + 8);  CSTEP(c1) c1 = WLD((OFF) + 9);         \
    CSTEP(c2) c2 = WLD((OFF) + 10); CSTEP(c3) c3 = WLD((OFF) + 11);        \
    CSTEP(c4) c4 = WLD((OFF) + 12); CSTEP(c5) c5 = WLD((OFF) + 13);        \
    CSTEP(c6) c6 = WLD((OFF) + 14); CSTEP(c7) c7 = WLD((OFF) + 15);
#define CGRP_L                                                             \
    CSTEP(c0) CSTEP(c1) CSTEP(c2) CSTEP(c3)                                \
    CSTEP(c4) CSTEP(c5) CSTEP(c6) CSTEP(c7)

// diet tail step (quadratic drift): inputs a, b2=2b
#define FSTEP(a, b2)                                                       \
    {                                                                      \
        float m_  = fmaf(-0.5f, (b2), (a));            /* a-b */           \
        float rn_ = r + fmaf(r, fmaf(r, -m_, -(b2)), (a));                 \
        float y_  = rn_ * C49; float y2_ = y_ * y_; float u_ = y2_ * y2_;  \
        float pl_ = fmaf(u_, -0.15625f, 0.25f);                            \
        r = rn_ - (rn_ * u_) * pl_;                                        \
    }

// emit step: tanh 2-term, divisor corrections first-order, full perc poly
#define ESTEP(a, b2, PS, PC)                                               \
    {                                                                      \
        float b_   = 0.5f * (b2);                                          \
        float tp_  = (a) * fmaf((a) * (a), -0.33333334f, 1.0f);            \
        float te_  = b_ * fmaf(b_ * b_, -0.33333334f, 1.0f);               \
        float q1_  = fmaf(-r, tp_, 1.0f);              /* 1-e1 */          \
        float dp_  = (tp_ * fmaf(-r, r, 1.0f)) * q1_;                      \
        float omr_ = 1.0f - r;                                             \
        float q2_  = fmaf(-te_, omr_, 1.0f);           /* 1-e2 */          \
        float de_  = ((r * (2.0f - r)) * te_) * q2_;                       \
        float rn_  = r + (dp_ - de_);                                      \
        float y_   = rn_ * C49; float y2_ = y_ * y_; float u_ = y2_ * y2_; \
        float pl_  = fmaf(u_, fmaf(u_, 0.1171875f, -0.15625f), 0.25f);     \
        float pcr_ = (rn_ * u_) * pl_;                                     \
        r = rn_ - pcr_;                                                    \
        PS = x1s * dp_;                                                    \
        PC = x1s * pcr_;                                                   \
    }

// consume ring slot + prefetch 4 ahead
#define FQ(RN, mm)                                                         \
    FSTEP(RN.x, RN.y)                                                      \
    RN = ((mm) < 12) ? RD(Sc, (mm) + 4) : RD(Sn, (mm) - 12);

// emit pair (guard m0<12: last needed load at m0=10 -> elements 14,15)
#define EPAIR2(RA, RB, m0)                                                 \
    {                                                                      \
        float psA, pcA, psB, pcB;                                          \
        ESTEP(RA.x, RA.y, psA, pcA)                                        \
        ESTEP(RB.x, RB.y, psB, pcB)                                        \
        *(float4*)(side + 2 * (size_t)(t0 + (m0))) =                       \
            make_float4(psA, pcA, psB, pcB);                               \
        sum4 += psA + psB; sq4 = fmaf(psA, psA, sq4); sq4 = fmaf(psB, psB, sq4); \
        sum5 += pcA + pcB; sq5 = fmaf(pcA, pcA, sq5); sq5 = fmaf(pcB, pcB, sq5); \
        if ((m0) < 12) { RA = RD(Se, (m0) + 4); RB = RD(Se, (m0) + 5); }   \
    }

__global__ __launch_bounds__(256, 2) void scan_kernel(const float4* __restrict__ x4,
                                                      const float* __restrict__ x1p,
                                                      float* __restrict__ side,
                                                      double* __restrict__ stats) {
    __shared__ float2 plane[LDSN];
    __shared__ float cA[NWIN + 1], cB[NWIN + 1], cC[NWIN + 1], cD[NWIN + 1];
    __shared__ double red[4][12];

    const float x1s    = x1p[0];
    const float inv_x1 = 1.0f / x1s;
    const float inv2x  = 2.0f * inv_x1;
    const float rmax   = 320.0f * inv_x1;
    const int k  = blockIdx.x * 256 + threadIdx.x;     // chunk id
    const int kp = threadIdx.x;
    const char* lbase = (const char*)plane;

    // ---- stage (a,2b) for elements [16k0-640, 16k0+4096+16) + cols0-3 stats
    float s0 = 0, s1 = 0, s2c = 0, s3 = 0, q0 = 0, q1 = 0, q2 = 0, q3 = 0;
    {
        const int g0 = 2048 * blockIdx.x - 320;        // float4 base
        for (int j = 0; j < 10; ++j) {
            int ts = threadIdx.x + 256 * j;
            if (ts < NSTAGE4) {
                int g4 = g0 + ts;
                float4 v = x4[min(max(g4, 0), X4MAX)];
                float pn0 = fmaxf(v.x - v.y, 0.0f), en0 = fmaxf(v.y - v.x, 0.0f);
                float pn1 = fmaxf(v.z - v.w, 0.0f), en1 = fmaxf(v.w - v.z, 0.0f);
                if (g4 < 0) { pn0 = en0 = pn1 = en1 = 0.0f; }
                plane[SWZ(2 * ts)]     = make_float2(pn0 * inv_x1, en0 * inv2x);
                plane[SWZ(2 * ts + 1)] = make_float2(pn1 * inv_x1, en1 * inv2x);
                if (ts >= 320 && ts < 2368) {          // owned emit region
                    s0 += v.x + v.z; q0 = fmaf(v.x, v.x, q0); q0 = fmaf(v.z, v.z, q0);
                    s1 += v.y + v.w; q1 = fmaf(v.y, v.y, q1); q1 = fmaf(v.w, v.w, q1);
                    s2c += pn0 + pn1; q2 = fmaf(pn0, pn0, q2); q2 = fmaf(pn1, pn1, q2);
                    s3 += en0 + en1; q3 = fmaf(en0, en0, q3); q3 = fmaf(en1, en1, q3);
                }
            }
        }
    }
    __syncthreads();

    // ---- per-window drift-cubic coeffs from staged plane (linear tanh) ----
    for (int wl = threadIdx.x; wl < NWIN; wl += 256) {
        const int Sw = SWZ(16 * wl) << 3;
        float Sa = 0, Sa2 = 0, Sb = 0, Sb2 = 0;
#pragma unroll
        for (int mm = 0; mm < 16; ++mm) {
            float2 p = RD(Sw, mm);
            Sa += p.x; Sa2 = fmaf(p.x, p.x, Sa2);
            Sb += p.y; Sb2 = fmaf(p.y, p.y, Sb2);
        }
        float Tp = Sa, Qp = Sa2, Te = 0.5f * Sb, Qe = 0.25f * Sb2;
        cA[wl] = Tp;
        cB[wl] = 2.0f * (Qe - Te) - Qp;
        cC[wl] = Te - Tp - 3.0f * Qe;
        cD[wl] = Qp + Qe;
    }
    __syncthreads();

    // ---- coarse phase: 32 windows ----
    float4 c0 = WLD(0), c1 = WLD(1), c2 = WLD(2), c3 = WLD(3),
           c4 = WLD(4), c5 = WLD(5), c6 = WLD(6), c7 = WLD(7);
    float r = 0.0f;
    CGRP_R(0) CGRP_R(8) CGRP_R(16) CGRP_L

    // ---- exact tail: 128 steps ----
    float2 r0, r1, r2, r3;
    {
        const int S0 = SWZ(16 * kp + 512) << 3;
        r0 = RD(S0, 0); r1 = RD(S0, 1); r2 = RD(S0, 2); r3 = RD(S0, 3);
    }
#pragma unroll 1
    for (int B = 0; B < NTAIL; B += 16) {
        const int W0 = 16 * kp + 512 + B;
        const int Sc = SWZ(W0) << 3;
        const int Sn = SWZ(W0 + 16) << 3;
        FQ(r0, 0)  FQ(r1, 1)  FQ(r2, 2)  FQ(r3, 3)
        FQ(r0, 4)  FQ(r1, 5)  FQ(r2, 6)  FQ(r3, 7)
        FQ(r0, 8)  FQ(r1, 9)  FQ(r2, 10) FQ(r3, 11)
        FQ(r0, 12) FQ(r1, 13) FQ(r2, 14) FQ(r3, 15)
    }

    // ---- exact emit: 16 steps ----
    float sum4 = 0, sum5 = 0, sq4 = 0, sq5 = 0;
    const int t0 = 16 * k;
    const int Se = SWZ(16 * kp + 512 + NTAIL) << 3;
    EPAIR2(r0, r1, 0)  EPAIR2(r2, r3, 2)
    EPAIR2(r0, r1, 4)  EPAIR2(r2, r3, 6)
    EPAIR2(r0, r1, 8)  EPAIR2(r2, r3, 10)
    EPAIR2(r0, r1, 12) EPAIR2(r2, r3, 14)

    // ---- block reduction -> one f64 atomic per channel ----
    double vv[12] = {s0, s1, s2c, s3, sum4, sum5,
                     q0, q1, q2, q3, sq4, sq5};
    const int wid = threadIdx.x >> 6, lane = threadIdx.x & 63;
#pragma unroll
    for (int c = 0; c < 12; ++c) {
        double val = vv[c];
        for (int off = 32; off > 0; off >>= 1) val += __shfl_down(val, off, 64);
        if (lane == 0) red[wid][c] = val;
    }
    __syncthreads();
    if (threadIdx.x < 12) {
        int c = threadIdx.x;
        double tot = red[0][c] + red[1][c] + red[2][c] + red[3][c];
        atomicAdd(&stats[c], tot);
    }
}

// ---------------- normalize (mu/sigma computed in prologue) ----------------
__global__ __launch_bounds__(256) void normalize_kernel(const float4* __restrict__ xp4,
                                                        const float4* __restrict__ side4,
                                                        float* __restrict__ out,
                                                        const double* __restrict__ stats) {
    __shared__ float sh[12];
    if (threadIdx.x < 6) {
        int c = threadIdx.x;
        double sum = stats[c], sumsq = stats[6 + c];
        double n = (double)T_TOTAL;
        double mu = sum / n;
        double var = (sumsq - sum * sum / n) / (n - 1.0);
        sh[c] = (float)mu;
        sh[6 + c] = (float)(1.0 / sqrt(var));
    }
    __syncthreads();
    float mu[6], is[6];
#pragma unroll
    for (int c = 0; c < 6; ++c) { mu[c] = sh[c]; is[c] = sh[6 + c]; }

    int idx = blockIdx.x * blockDim.x + threadIdx.x;
    int stride = gridDim.x * blockDim.x;
    for (int p = idx; p < T_TOTAL / 2; p += stride) {
        float4 xv = xp4[p];
        float* o = out + 12 * (size_t)p;
        float4 sv = side4[p];
        float pn0 = fmaxf(xv.x - xv.y, 0.0f), en0 = fmaxf(xv.y - xv.x, 0.0f);
        float pn1 = fmaxf(xv.z - xv.w, 0.0f), en1 = fmaxf(xv.w - xv.z, 0.0f);
        float4 o0 = {(xv.x - mu[0]) * is[0], (xv.y - mu[1]) * is[1],
                     (pn0 - mu[2]) * is[2], (en0 - mu[3]) * is[3]};
        float4 o1 = {(sv.x - mu[4]) * is[4], (sv.y - mu[5]) * is[5],
                     (xv.z - mu[0]) * is[0], (xv.w - mu[1]) * is[1]};
        float4 o2 = {(pn1 - mu[2]) * is[2], (en1 - mu[3]) * is[3],
                     (sv.z - mu[4]) * is[4], (sv.w - mu[5]) * is[5]};
        *(float4*)(o + 0) = o0;
        *(float4*)(o + 4) = o1;
        *(float4*)(o + 8) = o2;
    }
}

extern "C" void kernel_launch(void* const* d_in, const int* in_sizes, int n_in,
                              void* d_out, int out_size, void* d_ws, size_t ws_size,
                              hipStream_t stream) {
    const float4* x4 = (const float4*)d_in[0];
    const float* x1 = (const float*)d_in[1];
    float* out = (float*)d_out;
    char* ws = (char*)d_ws;
    double* stats = (double*)(ws + OFF_STATS);
    float* side = (float*)(ws + OFF_SIDE);

    hipMemsetAsync(stats, 0, 12 * sizeof(double), stream);
    scan_kernel<<<NBLOCKS, THREADS, 0, stream>>>(x4, x1, side, stats);
    normalize_kernel<<<2048, 256, 0, stream>>>(x4, (const float4*)side, out, stats);
}

// Round 22
// 48.440 us; speedup vs baseline: 1.8561x; 1.0351x over previous
//
#include <hip/hip_runtime.h>
#include <hip/hip_fp16.h>

// T=2^21 sequential nonlinear storage recurrence + per-column z-score.
// R22 = R21 with the side buffer in fp16 (__half2 per row, packed 8B stores):
// ps/perc only face sigma~O(1) in normalization -> fp16 err ~0.003 normalized
// (margin 0.05). Saves 8.4MB write (scan) + 8.4MB read (normalize) ~ 2.5us.
// Structure: memset(96B) -> scan (stats via f64 atomics) -> normalize.

#define T_TOTAL   (1 << 21)
#define C_CHUNKS  (T_TOTAL / 16)             // 131072
#define NTAIL     128
#define THREADS   256
#define NBLOCKS   (C_CHUNKS / THREADS)       // 512 -> 2 blocks/CU
#define NSTAGE4   2376                       // float4s staged per block
#define LDSN      4768                       // float2 slots (need 4752)
#define NWIN      287                        // windows per block
#define X4MAX     (T_TOTAL / 2 - 1)
#define C49       0.44444445f

// ws layout (bytes)
#define OFF_STATS 0                                   // 12 double
#define OFF_SIDE  1024                                // T __half2 (ps,perc)

#define SWZ(w) ((w) ^ (((w) >> 4) & 31))
#define RD(Sb, mm) (*(const float2*)(lbase + ((Sb) ^ ((mm) << 3))))
#define CL(v) fminf(fmaxf((v), 0.0f), rmax)

// window drift: cubic + 16x perc (3-term)
#define DRIFT(RV, C, OUT)                                                  \
    {                                                                      \
        float rr_ = (RV);                                                  \
        float d_ = fmaf(rr_, fmaf(rr_, fmaf(rr_, (C).w, (C).z), (C).y), (C).x); \
        float y_  = rr_ * C49;                                             \
        float y2_ = y_ * y_;                                               \
        float u_  = y2_ * y2_;                                             \
        float pl_ = fmaf(u_, fmaf(u_, 1.875f, -2.5f), 4.0f);               \
        OUT = d_ - (rr_ * u_) * pl_;                                       \
    }

#define CSTEP(C)                                                           \
    {                                                                      \
        float k1_, k2_;                                                    \
        DRIFT(r, C, k1_)                                                   \
        float sm_ = CL(r + k1_);                                           \
        DRIFT(sm_, C, k2_)                                                 \
        r = CL(fmaf(0.5f, k1_ + k2_, r));                                  \
    }

#define WLD(j) make_float4(cA[kp + (j)], cB[kp + (j)], cC[kp + (j)], cD[kp + (j)])

#define CGRP_R(OFF)                                                        \
    CSTEP(c0) c0 = WLD((OFF) + 8);  CSTEP(c1) c1 = WLD((OFF) + 9);         \
    CSTEP(c2) c2 = WLD((OFF) + 10); CSTEP(c3) c3 = WLD((OFF) + 11);        \
    CSTEP(c4) c4 = WLD((OFF) + 12); CSTEP(c5) c5 = WLD((OFF) + 13);        \
    CSTEP(c6) c6 = WLD((OFF) + 14); CSTEP(c7) c7 = WLD((OFF) + 15);
#define CGRP_L                                                             \
    CSTEP(c0) CSTEP(c1) CSTEP(c2) CSTEP(c3)                                \
    CSTEP(c4) CSTEP(c5) CSTEP(c6) CSTEP(c7)

// diet tail step (quadratic drift): inputs a, b2=2b
#define FSTEP(a, b2)                                                       \
    {                                                                      \
        float m_  = fmaf(-0.5f, (b2), (a));            /* a-b */           \
        float rn_ = r + fmaf(r, fmaf(r, -m_, -(b2)), (a));                 \
        float y_  = rn_ * C49; float y2_ = y_ * y_; float u_ = y2_ * y2_;  \
        float pl_ = fmaf(u_, -0.15625f, 0.25f);                            \
        r = rn_ - (rn_ * u_) * pl_;                                        \
    }

// emit step: tanh 2-term, divisor corrections first-order, full perc poly
#define ESTEP(a, b2, PS, PC)                                               \
    {                                                                      \
        float b_   = 0.5f * (b2);                                          \
        float tp_  = (a) * fmaf((a) * (a), -0.33333334f, 1.0f);            \
        float te_  = b_ * fmaf(b_ * b_, -0.33333334f, 1.0f);               \
        float q1_  = fmaf(-r, tp_, 1.0f);              /* 1-e1 */          \
        float dp_  = (tp_ * fmaf(-r, r, 1.0f)) * q1_;                      \
        float omr_ = 1.0f - r;                                             \
        float q2_  = fmaf(-te_, omr_, 1.0f);           /* 1-e2 */          \
        float de_  = ((r * (2.0f - r)) * te_) * q2_;                       \
        float rn_  = r + (dp_ - de_);                                      \
        float y_   = rn_ * C49; float y2_ = y_ * y_; float u_ = y2_ * y2_; \
        float pl_  = fmaf(u_, fmaf(u_, 0.1171875f, -0.15625f), 0.25f);     \
        float pcr_ = (rn_ * u_) * pl_;                                     \
        r = rn_ - pcr_;                                                    \
        PS = x1s * dp_;                                                    \
        PC = x1s * pcr_;                                                   \
    }

// consume ring slot + prefetch 4 ahead
#define FQ(RN, mm)                                                         \
    FSTEP(RN.x, RN.y)                                                      \
    RN = ((mm) < 12) ? RD(Sc, (mm) + 4) : RD(Sn, (mm) - 12);

// emit pair -> packed 8B fp16 store (2 rows)
#define EPAIR2(RA, RB, m0)                                                 \
    {                                                                      \
        float psA, pcA, psB, pcB;                                          \
        ESTEP(RA.x, RA.y, psA, pcA)                                        \
        ESTEP(RB.x, RB.y, psB, pcB)                                        \
        __half2 hA_ = __floats2half2_rn(psA, pcA);                         \
        __half2 hB_ = __floats2half2_rn(psB, pcB);                         \
        *(uint2*)(side + (size_t)(t0 + (m0))) =                            \
            make_uint2(*(unsigned*)&hA_, *(unsigned*)&hB_);                \
        sum4 += psA + psB; sq4 = fmaf(psA, psA, sq4); sq4 = fmaf(psB, psB, sq4); \
        sum5 += pcA + pcB; sq5 = fmaf(pcA, pcA, sq5); sq5 = fmaf(pcB, pcB, sq5); \
        if ((m0) < 12) { RA = RD(Se, (m0) + 4); RB = RD(Se, (m0) + 5); }   \
    }

__global__ __launch_bounds__(256, 2) void scan_kernel(const float4* __restrict__ x4,
                                                      const float* __restrict__ x1p,
                                                      __half2* __restrict__ side,
                                                      double* __restrict__ stats) {
    __shared__ float2 plane[LDSN];
    __shared__ float cA[NWIN + 1], cB[NWIN + 1], cC[NWIN + 1], cD[NWIN + 1];
    __shared__ double red[4][12];

    const float x1s    = x1p[0];
    const float inv_x1 = 1.0f / x1s;
    const float inv2x  = 2.0f * inv_x1;
    const float rmax   = 320.0f * inv_x1;
    const int k  = blockIdx.x * 256 + threadIdx.x;     // chunk id
    const int kp = threadIdx.x;
    const char* lbase = (const char*)plane;

    // ---- stage (a,2b) for elements [16k0-640, 16k0+4096+16) + cols0-3 stats
    float s0 = 0, s1 = 0, s2c = 0, s3 = 0, q0 = 0, q1 = 0, q2 = 0, q3 = 0;
    {
        const int g0 = 2048 * blockIdx.x - 320;        // float4 base
        for (int j = 0; j < 10; ++j) {
            int ts = threadIdx.x + 256 * j;
            if (ts < NSTAGE4) {
                int g4 = g0 + ts;
                float4 v = x4[min(max(g4, 0), X4MAX)];
                float pn0 = fmaxf(v.x - v.y, 0.0f), en0 = fmaxf(v.y - v.x, 0.0f);
                float pn1 = fmaxf(v.z - v.w, 0.0f), en1 = fmaxf(v.w - v.z, 0.0f);
                if (g4 < 0) { pn0 = en0 = pn1 = en1 = 0.0f; }
                plane[SWZ(2 * ts)]     = make_float2(pn0 * inv_x1, en0 * inv2x);
                plane[SWZ(2 * ts + 1)] = make_float2(pn1 * inv_x1, en1 * inv2x);
                if (ts >= 320 && ts < 2368) {          // owned emit region
                    s0 += v.x + v.z; q0 = fmaf(v.x, v.x, q0); q0 = fmaf(v.z, v.z, q0);
                    s1 += v.y + v.w; q1 = fmaf(v.y, v.y, q1); q1 = fmaf(v.w, v.w, q1);
                    s2c += pn0 + pn1; q2 = fmaf(pn0, pn0, q2); q2 = fmaf(pn1, pn1, q2);
                    s3 += en0 + en1; q3 = fmaf(en0, en0, q3); q3 = fmaf(en1, en1, q3);
                }
            }
        }
    }
    __syncthreads();

    // ---- per-window drift-cubic coeffs from staged plane (linear tanh) ----
    for (int wl = threadIdx.x; wl < NWIN; wl += 256) {
        const int Sw = SWZ(16 * wl) << 3;
        float Sa = 0, Sa2 = 0, Sb = 0, Sb2 = 0;
#pragma unroll
        for (int mm = 0; mm < 16; ++mm) {
            float2 p = RD(Sw, mm);
            Sa += p.x; Sa2 = fmaf(p.x, p.x, Sa2);
            Sb += p.y; Sb2 = fmaf(p.y, p.y, Sb2);
        }
        float Tp = Sa, Qp = Sa2, Te = 0.5f * Sb, Qe = 0.25f * Sb2;
        cA[wl] = Tp;
        cB[wl] = 2.0f * (Qe - Te) - Qp;
        cC[wl] = Te - Tp - 3.0f * Qe;
        cD[wl] = Qp + Qe;
    }
    __syncthreads();

    // ---- coarse phase: 32 windows ----
    float4 c0 = WLD(0), c1 = WLD(1), c2 = WLD(2), c3 = WLD(3),
           c4 = WLD(4), c5 = WLD(5), c6 = WLD(6), c7 = WLD(7);
    float r = 0.0f;
    CGRP_R(0) CGRP_R(8) CGRP_R(16) CGRP_L

    // ---- exact tail: 128 steps ----
    float2 r0, r1, r2, r3;
    {
        const int S0 = SWZ(16 * kp + 512) << 3;
        r0 = RD(S0, 0); r1 = RD(S0, 1); r2 = RD(S0, 2); r3 = RD(S0, 3);
    }
#pragma unroll 1
    for (int B = 0; B < NTAIL; B += 16) {
        const int W0 = 16 * kp + 512 + B;
        const int Sc = SWZ(W0) << 3;
        const int Sn = SWZ(W0 + 16) << 3;
        FQ(r0, 0)  FQ(r1, 1)  FQ(r2, 2)  FQ(r3, 3)
        FQ(r0, 4)  FQ(r1, 5)  FQ(r2, 6)  FQ(r3, 7)
        FQ(r0, 8)  FQ(r1, 9)  FQ(r2, 10) FQ(r3, 11)
        FQ(r0, 12) FQ(r1, 13) FQ(r2, 14) FQ(r3, 15)
    }

    // ---- exact emit: 16 steps ----
    float sum4 = 0, sum5 = 0, sq4 = 0, sq5 = 0;
    const int t0 = 16 * k;
    const int Se = SWZ(16 * kp + 512 + NTAIL) << 3;
    EPAIR2(r0, r1, 0)  EPAIR2(r2, r3, 2)
    EPAIR2(r0, r1, 4)  EPAIR2(r2, r3, 6)
    EPAIR2(r0, r1, 8)  EPAIR2(r2, r3, 10)
    EPAIR2(r0, r1, 12) EPAIR2(r2, r3, 14)

    // ---- block reduction -> one f64 atomic per channel ----
    double vv[12] = {s0, s1, s2c, s3, sum4, sum5,
                     q0, q1, q2, q3, sq4, sq5};
    const int wid = threadIdx.x >> 6, lane = threadIdx.x & 63;
#pragma unroll
    for (int c = 0; c < 12; ++c) {
        double val = vv[c];
        for (int off = 32; off > 0; off >>= 1) val += __shfl_down(val, off, 64);
        if (lane == 0) red[wid][c] = val;
    }
    __syncthreads();
    if (threadIdx.x < 12) {
        int c = threadIdx.x;
        double tot = red[0][c] + red[1][c] + red[2][c] + red[3][c];
        atomicAdd(&stats[c], tot);
    }
}

// ---------------- normalize (mu/sigma computed in prologue) ----------------
__global__ __launch_bounds__(256) void normalize_kernel(const float4* __restrict__ xp4,
                                                        const uint2* __restrict__ sideu,
                                                        float* __restrict__ out,
                                                        const double* __restrict__ stats) {
    __shared__ float sh[12];
    if (threadIdx.x < 6) {
        int c = threadIdx.x;
        double sum = stats[c], sumsq = stats[6 + c];
        double n = (double)T_TOTAL;
        double mu = sum / n;
        double var = (sumsq - sum * sum / n) / (n - 1.0);
        sh[c] = (float)mu;
        sh[6 + c] = (float)(1.0 / sqrt(var));
    }
    __syncthreads();
    float mu[6], is[6];
#pragma unroll
    for (int c = 0; c < 6; ++c) { mu[c] = sh[c]; is[c] = sh[6 + c]; }

    int idx = blockIdx.x * blockDim.x + threadIdx.x;
    int stride = gridDim.x * blockDim.x;
    for (int p = idx; p < T_TOTAL / 2; p += stride) {
        float4 xv = xp4[p];
        float* o = out + 12 * (size_t)p;
        uint2 su = sideu[p];                           // rows 2p, 2p+1 (fp16)
        float2 P0 = __half22float2(*(__half2*)&su.x);
        float2 P1 = __half22float2(*(__half2*)&su.y);
        float pn0 = fmaxf(xv.x - xv.y, 0.0f), en0 = fmaxf(xv.y - xv.x, 0.0f);
        float pn1 = fmaxf(xv.z - xv.w, 0.0f), en1 = fmaxf(xv.w - xv.z, 0.0f);
        float4 o0 = {(xv.x - mu[0]) * is[0], (xv.y - mu[1]) * is[1],
                     (pn0 - mu[2]) * is[2], (en0 - mu[3]) * is[3]};
        float4 o1 = {(P0.x - mu[4]) * is[4], (P0.y - mu[5]) * is[5],
                     (xv.z - mu[0]) * is[0], (xv.w - mu[1]) * is[1]};
        float4 o2 = {(pn1 - mu[2]) * is[2], (en1 - mu[3]) * is[3],
                     (P1.x - mu[4]) * is[4], (P1.y - mu[5]) * is[5]};
        *(float4*)(o + 0) = o0;
        *(float4*)(o + 4) = o1;
        *(float4*)(o + 8) = o2;
    }
}

extern "C" void kernel_launch(void* const* d_in, const int* in_sizes, int n_in,
                              void* d_out, int out_size, void* d_ws, size_t ws_size,
                              hipStream_t stream) {
    const float4* x4 = (const float4*)d_in[0];
    const float* x1 = (const float*)d_in[1];
    float* out = (float*)d_out;
    char* ws = (char*)d_ws;
    double* stats = (double*)(ws + OFF_STATS);
    __half2* side = (__half2*)(ws + OFF_SIDE);

    hipMemsetAsync(stats, 0, 12 * sizeof(double), stream);
    scan_kernel<<<NBLOCKS, THREADS, 0, stream>>>(x4, x1, side, stats);
    normalize_kernel<<<2048, 256, 0, stream>>>(x4, (const uint2*)side, out, stats);
}